// Round 7
// baseline (198.866 us; speedup 1.0000x reference)
//
#include <hip/hip_runtime.h>

#define NPTS      10000
#define NPTS_PAD  10240          // 128 chunks x 40 pairs x 2
#define NRAYS     4096
#define CHUNKS    128
#define PAIRS     40             // pairs per chunk
#define NPAIRS    (NPTS_PAD / 2) // 5120
#define PT_BLOCKS (NPTS_PAD / 256) // 40
#define PAIR_DW   108            // dwords per pair: geo 10 + pad 2 + shc 96
#define CHUNK_DW  (PAIRS * PAIR_DW)      // 4320 dwords = 17280 B
#define CHUNK_F4  (CHUNK_DW / 4)         // 1080 float4
#define LOG2E     1.44269504f

typedef float v2 __attribute__((ext_vector_type(2)));

// ---- static device scratch ----
// g_pk: per pair, 108 dwords:
//   [0]x0 x1 [2]y0 y1 [4]z0 z1 [6]w1_0 w1_1 [8]w0_0 w0_1 [10]pad2 [12..107] shc[i*2+b]
//   (w1 = -delta*log2e, w0 = sigma*opacity; i = k*3+ch, b = point-in-pair)
__device__ float4 g_pk4[NPAIRS * (PAIR_DW / 4)];
__device__ float  g_rays[NRAYS * 24];   // ox,oy,oz, dx,dy,dz, sh[16], pad2
__device__ float  g_acc [NRAYS * 5];    // Sr,Sg,Sb,Sd,S
__device__ float  g_oppart[PT_BLOCKS];  // per-block opacity partial sums

__device__ __forceinline__ float fast_rcp(float x)  { return __builtin_amdgcn_rcpf(x); }
__device__ __forceinline__ float fast_exp2(float x) { return __builtin_amdgcn_exp2f(x); }
__device__ __forceinline__ float fast_sigmoid(float x) { return fast_rcp(1.0f + fast_exp2(-x * LOG2E)); }

__device__ __forceinline__ v2 v2splat(float s) { v2 r; r.x = s; r.y = s; return r; }
__device__ __forceinline__ v2 fmav(v2 a, v2 b, v2 c) { return __builtin_elementwise_fma(a, b, c); }
__device__ __forceinline__ v2 exp2v(v2 a) { v2 r; r.x = fast_exp2(a.x); r.y = fast_exp2(a.y); return r; }
__device__ __forceinline__ v2 rsqv(v2 a)  { v2 r; r.x = __builtin_amdgcn_rsqf(a.x); r.y = __builtin_amdgcn_rsqf(a.y); return r; }
__device__ __forceinline__ v2 rcpv(v2 a)  { v2 r; r.x = fast_rcp(a.x); r.y = fast_rcp(a.y); return r; }

// ---------------- Kernel 1: merged setup (rays + points) ---------------------
__global__ __launch_bounds__(256) void setup(const float* __restrict__ ro,
                                             const float* __restrict__ rd,
                                             const float* __restrict__ pos,
                                             const int*   __restrict__ sidx,
                                             const float* __restrict__ log_delta,
                                             const float* __restrict__ log_sigma,
                                             const float* __restrict__ raw_op,
                                             const float* __restrict__ shc) {
    if (blockIdx.x < 16) {
        int r = blockIdx.x * 256 + threadIdx.x;
        float* a = g_acc + (size_t)r * 5;
        a[0] = a[1] = a[2] = a[3] = a[4] = 0.0f;

        float ox = ro[r * 3 + 0], oy = ro[r * 3 + 1], oz = ro[r * 3 + 2];
        float dx = rd[r * 3 + 0], dy = rd[r * 3 + 1], dz = rd[r * 3 + 2];
        float inv = __builtin_amdgcn_rsqf(dx * dx + dy * dy + dz * dz);
        float x = dx * inv, y = dy * inv, z = dz * inv;
        float* o = g_rays + (size_t)r * 24;
        o[0] = ox; o[1] = oy; o[2] = oz;
        o[3] = x;  o[4] = y;  o[5] = z;
        float* sh = o + 6;
        float zz = z * z, xx = x * x, yy = y * y;
        sh[0]  = 0.282095f;
        sh[1]  = 0.488603f * y;
        sh[2]  = 0.488603f * z;
        sh[3]  = 0.488603f * x;
        sh[4]  = 1.092548f * x * y;
        sh[5]  = 1.092548f * y * z;
        sh[6]  = 0.315392f * (3.0f * zz - 1.0f);
        sh[7]  = 1.092548f * x * z;
        sh[8]  = 0.546274f * (xx - yy);
        sh[9]  = 0.590044f * y * (3.0f * xx - yy);
        sh[10] = 2.890611f * x * y * z;
        sh[11] = 0.457046f * y * (5.0f * zz - 1.0f);
        sh[12] = 0.373176f * z * (5.0f * zz - 3.0f);
        sh[13] = 0.457046f * x * (5.0f * zz - 1.0f);
        sh[14] = 1.445306f * z * (xx - yy);
        sh[15] = 0.590044f * x * (xx - 3.0f * yy);
    } else {
        int pb = blockIdx.x - 16;
        int n  = pb * 256 + threadIdx.x;        // [0, NPTS_PAD)
        int j  = n >> 1, b = n & 1;
        float* o = (float*)g_pk4 + (size_t)j * PAIR_DW;
        float op = 0.0f;
        if (n < NPTS) {
            o[0 + b] = pos[n * 3 + 0];
            o[2 + b] = pos[n * 3 + 1];
            o[4 + b] = pos[n * 3 + 2];
            int s = sidx[n];
            op = fast_sigmoid(raw_op[n]);
            o[6 + b] = -__expf(log_delta[s]) * LOG2E;
            o[8 + b] =  __expf(log_sigma[s]) * op;
            o[10 + b] = 0.0f;
            const float* src = shc + (size_t)n * 48;
#pragma unroll
            for (int i = 0; i < 48; ++i) o[12 + i * 2 + b] = src[i];
        } else {
            o[0 + b] = 1e3f; o[2 + b] = 1e3f; o[4 + b] = 1e3f;
            o[6 + b] = 0.0f; o[8 + b] = 0.0f;   // w0=0 -> zero contribution
            o[10 + b] = 0.0f;
#pragma unroll
            for (int i = 0; i < 48; ++i) o[12 + i * 2 + b] = 0.0f;
        }
        __shared__ float blk;
        if (threadIdx.x == 0) blk = 0.0f;
        __syncthreads();
        float v = op;
#pragma unroll
        for (int off = 32; off > 0; off >>= 1) v += __shfl_down(v, off, 64);
        if ((threadIdx.x & 63) == 0) atomicAdd(&blk, v);
        __syncthreads();
        if (threadIdx.x == 0) g_oppart[pb] = blk;
    }
}

// ---------------- Kernel 2: main — LDS-staged chunk, packed f32 --------------
__global__ __launch_bounds__(256) void nerf_main() {
    __shared__ float4 sm4[CHUNK_F4];        // 17280 B: whole chunk in LDS
    float* sm = (float*)sm4;

    int rb = blockIdx.x & 15;     // 16 ray blocks of 256 rays
    int ch = blockIdx.x >> 4;     // CHUNKS point chunks
    int r  = rb * 256 + threadIdx.x;

    // stage chunk into LDS with coalesced vector loads
    {
        const float4* s4 = g_pk4 + (size_t)ch * CHUNK_F4;
#pragma unroll
        for (int i = threadIdx.x; i < CHUNK_F4; i += 256) sm4[i] = s4[i];
    }

    const float* rp = g_rays + (size_t)r * 24;
    v2 ox2 = v2splat(rp[0]), oy2 = v2splat(rp[1]), oz2 = v2splat(rp[2]);
    v2 dx2 = v2splat(rp[3]), dy2 = v2splat(rp[4]), dz2 = v2splat(rp[5]);
    v2 sh2[16];
#pragma unroll
    for (int k = 0; k < 16; ++k) sh2[k] = v2splat(rp[6 + k]);

    const v2 one2 = v2splat(1.0f);
    const v2 nl2e = v2splat(-LOG2E);

    __syncthreads();

    v2 S = v2splat(0.0f), Sd = S, Sr = S, Sg = S, Sb = S;
    for (int j = 0; j < PAIRS; ++j) {
        const v2* q = (const v2*)(sm + j * PAIR_DW);        // uniform -> broadcast
        v2 px = q[0], py = q[1], pz = q[2], w1 = q[3], w0 = q[4];

        v2 rx = px - ox2, ry = py - oy2, rz = pz - oz2;
        v2 d2 = rx * rx; d2 = fmav(ry, ry, d2); d2 = fmav(rz, rz, d2);
        v2 inv  = rsqv(d2);
        v2 dist = d2 * inv;
        v2 dn = rx * dx2; dn = fmav(ry, dy2, dn); dn = fmav(rz, dz2, dn);
        v2 t  = one2 - dn * inv;
        v2 e  = exp2v(w1 * t * t);
        v2 contrib = e * w0 * inv;

        S  = S + contrib;
        Sd = fmav(dist, contrib, Sd);

        const v2* c = (const v2*)(sm + j * PAIR_DW + 12);
        v2 s0 = c[0] * sh2[0], s1 = c[1] * sh2[0], s2 = c[2] * sh2[0];
#pragma unroll
        for (int k = 1; k < 16; ++k) {
            s0 = fmav(c[k * 3 + 0], sh2[k], s0);
            s1 = fmav(c[k * 3 + 1], sh2[k], s1);
            s2 = fmav(c[k * 3 + 2], sh2[k], s2);
        }
        v2 a0 = one2 + exp2v(s0 * nl2e);
        v2 a1 = one2 + exp2v(s1 * nl2e);
        v2 a2 = one2 + exp2v(s2 * nl2e);
        v2 ab  = a0 * a1;
        v2 CI  = contrib * rcpv(ab * a2);
        Sr = fmav(CI, a1 * a2, Sr);
        Sg = fmav(CI, a0 * a2, Sg);
        Sb = fmav(CI, ab, Sb);
    }

    float* a = g_acc + (size_t)r * 5;
    atomicAdd(a + 0, Sr.x + Sr.y);
    atomicAdd(a + 1, Sg.x + Sg.y);
    atomicAdd(a + 2, Sb.x + Sb.y);
    atomicAdd(a + 3, Sd.x + Sd.y);
    atomicAdd(a + 4, S.x  + S.y);
}

// ---------------- Kernel 3: finalize (f32 output) ----------------------------
__global__ void finalize(float* __restrict__ out) {
    int r = blockIdx.x * blockDim.x + threadIdx.x;
    if (r >= NRAYS) return;
    float opv = 0.0f;
#pragma unroll
    for (int i = 0; i < PT_BLOCKS; ++i) opv += g_oppart[i];
    const float* a = g_acc + (size_t)r * 5;
    float inv = fast_rcp(a[4] + 1e-8f);
    out[r * 3 + 0]     = a[0] * inv;
    out[r * 3 + 1]     = a[1] * inv;
    out[r * 3 + 2]     = a[2] * inv;
    out[NRAYS * 3 + r] = a[3] * inv;
    out[NRAYS * 4 + r] = opv * (1.0f / NPTS);
}

extern "C" void kernel_launch(void* const* d_in, const int* in_sizes, int n_in,
                              void* d_out, int out_size, void* d_ws, size_t ws_size,
                              hipStream_t stream) {
    const float* rays_o    = (const float*)d_in[0];
    const float* rays_d    = (const float*)d_in[1];
    const float* positions = (const float*)d_in[2];
    const int*   sidx      = (const int*)d_in[3];
    const float* log_delta = (const float*)d_in[4];
    const float* log_sigma = (const float*)d_in[5];
    const float* raw_op    = (const float*)d_in[6];
    const float* shc       = (const float*)d_in[7];

    setup<<<16 + PT_BLOCKS, 256, 0, stream>>>(
        rays_o, rays_d, positions, sidx, log_delta, log_sigma, raw_op, shc);
    nerf_main<<<16 * CHUNKS, 256, 0, stream>>>();
    finalize<<<NRAYS / 256, 256, 0, stream>>>((float*)d_out);
}

// Round 8
// 187.056 us; speedup vs baseline: 1.0631x; 1.0631x over previous
//
#include <hip/hip_runtime.h>

#define NPTS      10000
#define NPTS_PAD  10240          // 128 chunks x 40 pairs x 2
#define NRAYS     4096
#define CHUNKS    128
#define PAIRS     40             // pairs per chunk
#define NPAIRS    (NPTS_PAD / 2) // 5120
#define PT_BLOCKS (NPTS_PAD / 256) // 40
#define PAIR_DW   108            // dwords per pair: geo 10 + pad 2 + shc 96
#define PAIR_F4   (PAIR_DW / 4)  // 27
#define CHUNK_DW  (PAIRS * PAIR_DW)      // 4320 dwords = 17280 B
#define CHUNK_F4  (CHUNK_DW / 4)         // 1080 float4
#define LOG2E     1.44269504f

typedef float v2 __attribute__((ext_vector_type(2)));

// ---- static device scratch ----
// g_pk: per pair, 108 dwords:
//   [0]x0 x1 [2]y0 y1 [4]z0 z1 [6]w1_0 w1_1 [8]w0_0 w0_1 [10]pad2 [12..107] shc[i*2+b]
//   (w1 = -delta*log2e, w0 = sigma*opacity; i = k*3+ch, b = point-in-pair)
__device__ float4 g_pk4[NPAIRS * PAIR_F4];
__device__ float  g_rays[NRAYS * 24];   // ox,oy,oz, dx,dy,dz, sh[16], pad2
__device__ float  g_acc [NRAYS * 5];    // Sr,Sg,Sb,Sd,S
__device__ float  g_oppart[PT_BLOCKS];  // per-block opacity partial sums

__device__ __forceinline__ float fast_rcp(float x)  { return __builtin_amdgcn_rcpf(x); }
__device__ __forceinline__ float fast_exp2(float x) { return __builtin_amdgcn_exp2f(x); }
__device__ __forceinline__ float fast_sigmoid(float x) { return fast_rcp(1.0f + fast_exp2(-x * LOG2E)); }

__device__ __forceinline__ v2 v2splat(float s) { v2 r; r.x = s; r.y = s; return r; }
__device__ __forceinline__ v2 fmav(v2 a, v2 b, v2 c) { return __builtin_elementwise_fma(a, b, c); }
__device__ __forceinline__ v2 exp2v(v2 a) { v2 r; r.x = fast_exp2(a.x); r.y = fast_exp2(a.y); return r; }
__device__ __forceinline__ v2 rsqv(v2 a)  { v2 r; r.x = __builtin_amdgcn_rsqf(a.x); r.y = __builtin_amdgcn_rsqf(a.y); return r; }
__device__ __forceinline__ v2 rcpv(v2 a)  { v2 r; r.x = fast_rcp(a.x); r.y = fast_rcp(a.y); return r; }
__device__ __forceinline__ v2 f4lo(float4 f) { v2 r; r.x = f.x; r.y = f.y; return r; }
__device__ __forceinline__ v2 f4hi(float4 f) { v2 r; r.x = f.z; r.y = f.w; return r; }

// ---------------- Kernel 1: merged setup (rays + points) ---------------------
__global__ __launch_bounds__(256) void setup(const float* __restrict__ ro,
                                             const float* __restrict__ rd,
                                             const float* __restrict__ pos,
                                             const int*   __restrict__ sidx,
                                             const float* __restrict__ log_delta,
                                             const float* __restrict__ log_sigma,
                                             const float* __restrict__ raw_op,
                                             const float* __restrict__ shc) {
    if (blockIdx.x < 16) {
        int r = blockIdx.x * 256 + threadIdx.x;
        float* a = g_acc + (size_t)r * 5;
        a[0] = a[1] = a[2] = a[3] = a[4] = 0.0f;

        float ox = ro[r * 3 + 0], oy = ro[r * 3 + 1], oz = ro[r * 3 + 2];
        float dx = rd[r * 3 + 0], dy = rd[r * 3 + 1], dz = rd[r * 3 + 2];
        float inv = __builtin_amdgcn_rsqf(dx * dx + dy * dy + dz * dz);
        float x = dx * inv, y = dy * inv, z = dz * inv;
        float* o = g_rays + (size_t)r * 24;
        o[0] = ox; o[1] = oy; o[2] = oz;
        o[3] = x;  o[4] = y;  o[5] = z;
        float* sh = o + 6;
        float zz = z * z, xx = x * x, yy = y * y;
        sh[0]  = 0.282095f;
        sh[1]  = 0.488603f * y;
        sh[2]  = 0.488603f * z;
        sh[3]  = 0.488603f * x;
        sh[4]  = 1.092548f * x * y;
        sh[5]  = 1.092548f * y * z;
        sh[6]  = 0.315392f * (3.0f * zz - 1.0f);
        sh[7]  = 1.092548f * x * z;
        sh[8]  = 0.546274f * (xx - yy);
        sh[9]  = 0.590044f * y * (3.0f * xx - yy);
        sh[10] = 2.890611f * x * y * z;
        sh[11] = 0.457046f * y * (5.0f * zz - 1.0f);
        sh[12] = 0.373176f * z * (5.0f * zz - 3.0f);
        sh[13] = 0.457046f * x * (5.0f * zz - 1.0f);
        sh[14] = 1.445306f * z * (xx - yy);
        sh[15] = 0.590044f * x * (xx - 3.0f * yy);
    } else {
        int pb = blockIdx.x - 16;
        int n  = pb * 256 + threadIdx.x;        // [0, NPTS_PAD)
        int j  = n >> 1, b = n & 1;
        float* o = (float*)g_pk4 + (size_t)j * PAIR_DW;
        float op = 0.0f;
        if (n < NPTS) {
            o[0 + b] = pos[n * 3 + 0];
            o[2 + b] = pos[n * 3 + 1];
            o[4 + b] = pos[n * 3 + 2];
            int s = sidx[n];
            op = fast_sigmoid(raw_op[n]);
            o[6 + b] = -__expf(log_delta[s]) * LOG2E;
            o[8 + b] =  __expf(log_sigma[s]) * op;
            o[10 + b] = 0.0f;
            const float* src = shc + (size_t)n * 48;
#pragma unroll
            for (int i = 0; i < 48; ++i) o[12 + i * 2 + b] = src[i];
        } else {
            o[0 + b] = 1e3f; o[2 + b] = 1e3f; o[4 + b] = 1e3f;
            o[6 + b] = 0.0f; o[8 + b] = 0.0f;   // w0=0 -> zero contribution
            o[10 + b] = 0.0f;
#pragma unroll
            for (int i = 0; i < 48; ++i) o[12 + i * 2 + b] = 0.0f;
        }
        __shared__ float blk;
        if (threadIdx.x == 0) blk = 0.0f;
        __syncthreads();
        float v = op;
#pragma unroll
        for (int off = 32; off > 0; off >>= 1) v += __shfl_down(v, off, 64);
        if ((threadIdx.x & 63) == 0) atomicAdd(&blk, v);
        __syncthreads();
        if (threadIdx.x == 0) g_oppart[pb] = blk;
    }
}

// ---------------- Kernel 2: main — LDS chunk, register-batched pair loads ----
// Pair data register map: global f4 index g = 3 + (i>>1) for SH coeff i;
// g<14 lives in BA[g], else BB[g-14]. All indices literal-constant via macros.
#define QREG(g) ((g) < 14 ? BA[(g)] : BB[(g) - 14])
#define CC(i)   (((i) & 1) ? f4hi(QREG(3 + ((i) >> 1))) : f4lo(QREG(3 + ((i) >> 1))))
#define SHK(k)  { v2 shk = v2splat(sh[k]);              \
    s0 = fmav(CC(3 * (k) + 0), shk, s0);                \
    s1 = fmav(CC(3 * (k) + 1), shk, s1);                \
    s2 = fmav(CC(3 * (k) + 2), shk, s2); }

__global__ __launch_bounds__(256, 3) void nerf_main() {
    __shared__ float4 sm4[CHUNK_F4];        // 17280 B: whole chunk in LDS

    int rb = blockIdx.x & 15;     // 16 ray blocks of 256 rays
    int ch = blockIdx.x >> 4;     // CHUNKS point chunks
    int r  = rb * 256 + threadIdx.x;

    // stage chunk into LDS with coalesced vector loads
    {
        const float4* s4 = g_pk4 + (size_t)ch * CHUNK_F4;
        for (int i = threadIdx.x; i < CHUNK_F4; i += 256) sm4[i] = s4[i];
    }

    const float* rp = g_rays + (size_t)r * 24;
    v2 ox2 = v2splat(rp[0]), oy2 = v2splat(rp[1]), oz2 = v2splat(rp[2]);
    v2 dx2 = v2splat(rp[3]), dy2 = v2splat(rp[4]), dz2 = v2splat(rp[5]);
    float sh[16];
#pragma unroll
    for (int k = 0; k < 16; ++k) sh[k] = rp[6 + k];

    const v2 one2 = v2splat(1.0f);
    const v2 nl2e = v2splat(-LOG2E);

    __syncthreads();

    v2 S = v2splat(0.0f), Sd = S, Sr = S, Sg = S, Sb = S;
    for (int j = 0; j < PAIRS; ++j) {
        const float4* pj = sm4 + j * PAIR_F4;

        // batch A: geo + first 22 SH coeff pairs (issued together)
        float4 BA[14];
#pragma unroll
        for (int i = 0; i < 14; ++i) BA[i] = pj[i];

        v2 px = f4lo(BA[0]), py = f4hi(BA[0]);
        v2 pz = f4lo(BA[1]), w1 = f4hi(BA[1]);
        v2 w0 = f4lo(BA[2]);

        v2 rx = px - ox2, ry = py - oy2, rz = pz - oz2;
        v2 d2 = rx * rx; d2 = fmav(ry, ry, d2); d2 = fmav(rz, rz, d2);
        v2 inv  = rsqv(d2);

        // batch B issued behind geometry compute; latency hides under SH part 1
        float4 BB[13];
#pragma unroll
        for (int i = 0; i < 13; ++i) BB[i] = pj[14 + i];

        v2 dn = rx * dx2; dn = fmav(ry, dy2, dn); dn = fmav(rz, dz2, dn);
        v2 t  = one2 - dn * inv;
        v2 e  = exp2v(w1 * t * t);
        v2 contrib = e * w0 * inv;

        S  = S + contrib;
        Sd = fmav(d2 * inv, contrib, Sd);

        v2 s0 = v2splat(0.0f), s1 = s0, s2 = s0;
        SHK(0)  SHK(1)  SHK(2)  SHK(3)  SHK(4)  SHK(5)  SHK(6)   // uses BA only
        SHK(7)  SHK(8)  SHK(9)  SHK(10) SHK(11) SHK(12)
        SHK(13) SHK(14) SHK(15)

        v2 a0 = one2 + exp2v(s0 * nl2e);
        v2 a1 = one2 + exp2v(s1 * nl2e);
        v2 a2 = one2 + exp2v(s2 * nl2e);
        v2 ab  = a0 * a1;
        v2 CI  = contrib * rcpv(ab * a2);
        Sr = fmav(CI, a1 * a2, Sr);
        Sg = fmav(CI, a0 * a2, Sg);
        Sb = fmav(CI, ab, Sb);
    }

    float* a = g_acc + (size_t)r * 5;
    atomicAdd(a + 0, Sr.x + Sr.y);
    atomicAdd(a + 1, Sg.x + Sg.y);
    atomicAdd(a + 2, Sb.x + Sb.y);
    atomicAdd(a + 3, Sd.x + Sd.y);
    atomicAdd(a + 4, S.x  + S.y);
}

// ---------------- Kernel 3: finalize (f32 output) ----------------------------
__global__ void finalize(float* __restrict__ out) {
    int r = blockIdx.x * blockDim.x + threadIdx.x;
    if (r >= NRAYS) return;
    float opv = 0.0f;
#pragma unroll
    for (int i = 0; i < PT_BLOCKS; ++i) opv += g_oppart[i];
    const float* a = g_acc + (size_t)r * 5;
    float inv = fast_rcp(a[4] + 1e-8f);
    out[r * 3 + 0]     = a[0] * inv;
    out[r * 3 + 1]     = a[1] * inv;
    out[r * 3 + 2]     = a[2] * inv;
    out[NRAYS * 3 + r] = a[3] * inv;
    out[NRAYS * 4 + r] = opv * (1.0f / NPTS);
}

extern "C" void kernel_launch(void* const* d_in, const int* in_sizes, int n_in,
                              void* d_out, int out_size, void* d_ws, size_t ws_size,
                              hipStream_t stream) {
    const float* rays_o    = (const float*)d_in[0];
    const float* rays_d    = (const float*)d_in[1];
    const float* positions = (const float*)d_in[2];
    const int*   sidx      = (const int*)d_in[3];
    const float* log_delta = (const float*)d_in[4];
    const float* log_sigma = (const float*)d_in[5];
    const float* raw_op    = (const float*)d_in[6];
    const float* shc       = (const float*)d_in[7];

    setup<<<16 + PT_BLOCKS, 256, 0, stream>>>(
        rays_o, rays_d, positions, sidx, log_delta, log_sigma, raw_op, shc);
    nerf_main<<<16 * CHUNKS, 256, 0, stream>>>();
    finalize<<<NRAYS / 256, 256, 0, stream>>>((float*)d_out);
}